// Round 1
// baseline (1342.013 us; speedup 1.0000x reference)
//
#include <hip/hip_runtime.h>
#include <hip/hip_bf16.h>

// B=2, S=2048 -> M=4096 tokens, K=4096, NN=11008, groupsize=128.
static constexpr int M  = 4096;
static constexpr int K  = 4096;
static constexpr int NN = 11008;

typedef _Float16 f16;
typedef _Float16 f16x2 __attribute__((ext_vector_type(2)));
typedef _Float16 f16x8 __attribute__((ext_vector_type(8)));
typedef float    f32x4 __attribute__((ext_vector_type(4)));

// ---------------------------------------------------------------------------
// GPTQ nibble j of an int32 covers k = 8r+j. The magic unpack emits the
// interleaved within-8 order [0,4,1,5,2,6,3,7]; all fp16 tensors (xp, Wc,
// Wd', h) use this same permutation along their reduction dim.
// Numerics: (1024+w) and (1025+z) are exact fp16 integers; their difference
// is exact; single rounding at the final mul by s.
// ---------------------------------------------------------------------------
union dq_u { f16x2 h[4]; f16x8 v; };

__device__ __forceinline__ f16x8 dq8(unsigned q, f16x2 s2, f16x2 zc2) {
    dq_u u;
    unsigned t0 = ( q         & 0x000F000Fu) | 0x64006400u;
    unsigned t1 = ((q >> 4)   & 0x000F000Fu) | 0x64006400u;
    unsigned t2 = ((q >> 8)   & 0x000F000Fu) | 0x64006400u;
    unsigned t3 = ((q >> 12)  & 0x000F000Fu) | 0x64006400u;
    u.h[0] = (__builtin_bit_cast(f16x2, t0) - zc2) * s2;
    u.h[1] = (__builtin_bit_cast(f16x2, t1) - zc2) * s2;
    u.h[2] = (__builtin_bit_cast(f16x2, t2) - zc2) * s2;
    u.h[3] = (__builtin_bit_cast(f16x2, t3) - zc2) * s2;
    return u.v;
}

// async global -> LDS, 16 B/lane; LDS dest = wave-uniform base + lane*16.
__device__ __forceinline__ void gll16(const f16* g, f16* l) {
    __builtin_amdgcn_global_load_lds(
        (const __attribute__((address_space(1))) unsigned int*)g,
        (__attribute__((address_space(3))) unsigned int*)l,
        16, 0, 0);
}

// ---------------------------------------------------------------------------
// Pre-pass: x fp32 -> fp16, permuted within each 8 along K.
// ---------------------------------------------------------------------------
__global__ __launch_bounds__(256) void convert_x_kernel(
    const float* __restrict__ x, f16* __restrict__ xp)
{
    size_t i = ((size_t)blockIdx.x * 256 + threadIdx.x) * 8;
    float4 f0 = *(const float4*)(x + i);
    float4 f1 = *(const float4*)(x + i + 4);
    f16x8 v;
    v[0] = (f16)f0.x; v[1] = (f16)f1.x;
    v[2] = (f16)f0.y; v[3] = (f16)f1.y;
    v[4] = (f16)f0.z; v[5] = (f16)f1.z;
    v[6] = (f16)f0.w; v[7] = (f16)f1.w;
    *(f16x8*)(xp + i) = v;
}

// ---------------------------------------------------------------------------
// Dequant strip: gate+up columns [n0, n0+NC) -> ONE interleaved matrix Wc:
// combined row j = (nl>>4)*32 + gu*16 + (nl&15), shape (2*NC, K) fp16.
// Even 16-blocks = gate, odd 16-blocks = up of the same 16 n's -> in the
// GEMM a wave's nt pairs (0,1),(2,3) hold (g,u) of the SAME column in the
// SAME lane. grid (NC/256, K/32).
// ---------------------------------------------------------------------------
__global__ __launch_bounds__(256) void dequant_gu_strip(
    const int* __restrict__ gqw, const float* __restrict__ gsc, const int* __restrict__ gqz,
    const int* __restrict__ uqw, const float* __restrict__ usc, const int* __restrict__ uqz,
    f16* __restrict__ wc, int n0)
{
    int nl = blockIdx.x * 256 + threadIdx.x;   // strip-local column
    int n  = n0 + nl;                          // global column
    int k0 = blockIdx.y * 32;
    int g  = k0 >> 7;
    int sh = (n & 7) * 4;

    float sgf = gsc[(size_t)g * NN + n];
    float suf = usc[(size_t)g * NN + n];
    int zg = (gqz[(size_t)g * (NN / 8) + (n >> 3)] >> sh) & 15;
    int zu = (uqz[(size_t)g * (NN / 8) + (n >> 3)] >> sh) & 15;
    f16 sgh = (f16)sgf, suh = (f16)suf;
    f16 zcg = (f16)(float)(1025 + zg);
    f16 zcu = (f16)(float)(1025 + zu);
    f16x2 s2g = {sgh, sgh}, zc2g = {zcg, zcg};
    f16x2 s2u = {suh, suh}, zc2u = {zcu, zcu};

    size_t jg = (size_t)((nl >> 4) * 32 + (nl & 15));
    size_t ju = jg + 16;

#pragma unroll
    for (int i = 0; i < 4; ++i) {
        unsigned qg = (unsigned)gqw[(size_t)(k0 / 8 + i) * NN + n];
        unsigned qu = (unsigned)uqw[(size_t)(k0 / 8 + i) * NN + n];
        *(f16x8*)&wc[jg * K + k0 + i * 8] = dq8(qg, s2g, zc2g);
        *(f16x8*)&wc[ju * K + k0 + i * 8] = dq8(qu, s2u, zc2u);
    }
}

// ---------------------------------------------------------------------------
// Dequant strip: down output columns [c0, c0+KC) -> wd as (KC, NN) fp16.
// grid (KC/256, NN/32).
// ---------------------------------------------------------------------------
__global__ __launch_bounds__(256) void dequant_d_strip(
    const int* __restrict__ dqw, const float* __restrict__ dsc, const int* __restrict__ dqz,
    f16* __restrict__ wd, int c0)
{
    int cl = blockIdx.x * 256 + threadIdx.x;
    int c  = c0 + cl;
    int n0 = blockIdx.y * 32;
    int g  = n0 >> 7;
    int sh = (c & 7) * 4;

    float sf = dsc[(size_t)g * K + c];
    int   z  = (dqz[(size_t)g * (K / 8) + (c >> 3)] >> sh) & 15;
    f16 shh = (f16)sf;
    f16 zch = (f16)(float)(1025 + z);
    f16x2 s2 = {shh, shh}, zc2 = {zch, zch};

#pragma unroll
    for (int i = 0; i < 4; ++i) {
        unsigned q = (unsigned)dqw[(size_t)(n0 / 8 + i) * K + c];
        *(f16x8*)&wd[(size_t)cl * NN + n0 + i * 8] = dq8(q, s2, zc2);
    }
}

// ---------------------------------------------------------------------------
// 256x256 8-phase GEMM (plain-HIP port of the verified m201 template).
// BK=64, 8 waves (2M x 4N), 512 threads, 128 KiB LDS (2 dbuf x 2 halves x
// 128x64 f16 for each of A,B). Per K-tile t (buffer d=t&1), 4 phases:
//   P0: ds_read A-mh0(8)+B-nh0(4); stage B1(t+1)->d^1; MFMA q(0,0); bar
//   P1: ds_read B-nh1(4);                              MFMA q(0,1); bar
//   P2: ds_read A-mh1(8); stage B0(t+2)->d;            MFMA q(1,0); bar
//   P3: stage A0,A1(t+2)->d;                           MFMA q(1,1);
//       s_waitcnt vmcnt(6); bar           // counted: 3 half-tiles in flight
// Safety invariants (verified on paper):
//  - every stage into a region happens >=1 barrier after that region's last
//    ds_read issue (A read P0/P2 -> staged P3; B0 read P0/P1 -> staged P2;
//    B1 staged in the *other* dbuf at P0).
//  - tile t is fully landed (all waves' slices) before group t's P0 reads:
//    each wave's own vmcnt(6) at group t-1's P3 drains through B1(t), then
//    the barrier publishes it.
// LDS swizzle: physical chunk = logical chunk ^ (row&7)  (row stride 128 B,
// 8x 16B chunks) -> exactly 8 lanes per bank-slot per wave = conflict-free.
// Staged with linear LDS dest + inverse-swizzled per-lane GLOBAL source.
// EPI=0: silu(g)*u -> h fp16 (interleaved Wc pairing); EPI=1: fp32 out.
// ---------------------------------------------------------------------------
template<int EPI>
__global__ __launch_bounds__(512) void gemm8p(
    const f16* __restrict__ Ag,   // (M, SK)
    const f16* __restrict__ Bg,   // (ncols_strip, SK) strip-local
    void*      __restrict__ Cv,
    const int SK, const int NT, const int cbase)
{
    __shared__ __align__(16) f16 LA[2][2][128 * 64];  // [dbuf][m-half] 64 KB
    __shared__ __align__(16) f16 LB[2][2][128 * 64];  // [dbuf][n-half] 64 KB

    const int tid  = threadIdx.x;
    const int lane = tid & 63;
    const int wave = tid >> 6;
    const int wm   = wave >> 2;          // A (M) half owned by this wave
    const int wbh  = (wave >> 1) & 1;    // B (N) half
    const int wnq  = wave & 1;           // 64-col quarter within B half
    const int quad = lane >> 4;
    const int lr   = lane & 15;

    const int m0  = blockIdx.x * 256;
    const int nb0 = blockIdx.y * 256;    // strip-local col base

    // staging constants: thread covers phys bytes (r*512+tid)*16 of a
    // half-tile; prow=(r*512+tid)>>3, pchunk=tid&7; source chunk is
    // inverse-swizzled so that swizzled ds_reads see logical data.
    const int trow = tid >> 3;                    // 0..63 (r adds 64)
    const int tch  = (tid & 7) ^ (trow & 7);      // (prow&7)==(trow&7) for both r
    const size_t arow = (size_t)(m0  + trow) * SK + (size_t)tch * 8;
    const size_t brow = (size_t)(nb0 + trow) * SK + (size_t)tch * 8;
    const int lstg = wave * 512;                  // + r*4096 elems

    // frag-read chunk offsets (elems), swizzle applied: chunk ^ (row&7)
    const int c0e = ((quad) ^ (lr & 7)) * 8;
    const int c1e = ((4 + quad) ^ (lr & 7)) * 8;

    f32x4 acc[8][4];
#pragma unroll
    for (int i = 0; i < 8; ++i)
#pragma unroll
        for (int j = 0; j < 4; ++j) acc[i][j] = (f32x4){0.f, 0.f, 0.f, 0.f};

    f16x8 a_[2][4];        // [kk][mt]  current quadrant-row of A
    f16x8 b_[2][2][2];     // [nh][kk][n2]

#define STAGE_A(D_, H_, T_) do {                                              \
    const f16* s_ = Ag + arow + (size_t)(H_) * 128 * SK + (size_t)(T_) * 64;  \
    gll16(s_, &LA[D_][H_][lstg]);                                             \
    gll16(s_ + (size_t)64 * SK, &LA[D_][H_][4096 + lstg]); } while (0)

#define STAGE_B(D_, H_, T_) do {                                              \
    const f16* s_ = Bg + brow + (size_t)(H_) * 128 * SK + (size_t)(T_) * 64;  \
    gll16(s_, &LB[D_][H_][lstg]);                                             \
    gll16(s_ + (size_t)64 * SK, &LB[D_][H_][4096 + lstg]); } while (0)

#define LOAD_A(D_, MH_) do {                                                  \
    _Pragma("unroll")                                                         \
    for (int mt = 0; mt < 4; ++mt) {                                          \
        a_[0][mt] = *(const f16x8*)&LA[D_][wm][((MH_) * 64 + mt * 16 + lr) * 64 + c0e]; \
        a_[1][mt] = *(const f16x8*)&LA[D_][wm][((MH_) * 64 + mt * 16 + lr) * 64 + c1e]; \
    } } while (0)

#define LOAD_B(D_, NH_) do {                                                  \
    _Pragma("unroll")                                                         \
    for (int n2 = 0; n2 < 2; ++n2) {                                          \
        b_[NH_][0][n2] = *(const f16x8*)&LB[D_][wbh][(wnq * 64 + (NH_) * 32 + n2 * 16 + lr) * 64 + c0e]; \
        b_[NH_][1][n2] = *(const f16x8*)&LB[D_][wbh][(wnq * 64 + (NH_) * 32 + n2 * 16 + lr) * 64 + c1e]; \
    } } while (0)

#define QMFMA(MH_, NH_) do {                                                  \
    __builtin_amdgcn_s_setprio(1);                                            \
    _Pragma("unroll")                                                         \
    for (int kk = 0; kk < 2; ++kk)                                            \
    _Pragma("unroll")                                                         \
    for (int n2 = 0; n2 < 2; ++n2)                                            \
    _Pragma("unroll")                                                         \
    for (int mt = 0; mt < 4; ++mt)                                            \
        acc[(MH_) * 4 + mt][(NH_) * 2 + n2] =                                 \
            __builtin_amdgcn_mfma_f32_16x16x32_f16(                           \
                a_[kk][mt], b_[NH_][kk][n2],                                  \
                acc[(MH_) * 4 + mt][(NH_) * 2 + n2], 0, 0, 0);                \
    __builtin_amdgcn_s_setprio(0); } while (0)

#define BAR() do { __builtin_amdgcn_s_barrier();                              \
                   __builtin_amdgcn_sched_barrier(0); } while (0)
#define WAITV6() do { asm volatile("s_waitcnt vmcnt(6)" ::: "memory");        \
                      __builtin_amdgcn_sched_barrier(0); } while (0)
#define WAITV0() do { asm volatile("s_waitcnt vmcnt(0)" ::: "memory");        \
                      __builtin_amdgcn_sched_barrier(0); } while (0)

    // prologue: tile0 fully, then B0/A0/A1 of tile1 (steady in-flight set)
    STAGE_A(0, 0, 0); STAGE_A(0, 1, 0); STAGE_B(0, 0, 0); STAGE_B(0, 1, 0);
    if (NT > 1) { STAGE_B(1, 0, 1); STAGE_A(1, 0, 1); STAGE_A(1, 1, 1); }
    if (NT > 1) { WAITV6(); } else { WAITV0(); }
    BAR();

#pragma unroll 2
    for (int t = 0; t < NT; ++t) {
        const int d  = t & 1;
        const int dn = d ^ 1;
        const bool s1 = (t + 1 < NT);
        const bool s2 = (t + 2 < NT);

        // P0
        LOAD_A(d, 0);
        LOAD_B(d, 0);
        if (s1) STAGE_B(dn, 1, t + 1);
        QMFMA(0, 0);
        BAR();
        // P1
        LOAD_B(d, 1);
        QMFMA(0, 1);
        BAR();
        // P2
        LOAD_A(d, 1);
        if (s2) STAGE_B(d, 0, t + 2);
        QMFMA(1, 0);
        BAR();
        // P3
        if (s2) { STAGE_A(d, 0, t + 2); STAGE_A(d, 1, t + 2); }
        QMFMA(1, 1);
        if (s2) { WAITV6(); } else { WAITV0(); }
        BAR();
    }

    if constexpr (EPI == 0) {
        // silu(g)*u -> h fp16; nt pairs (2p, 2p+1) = (gate, up) of same n.
        f16* __restrict__ h = (f16*)Cv;
        const int jw = cbase + nb0 + wbh * 128 + wnq * 64;   // global combined col
#pragma unroll
        for (int p = 0; p < 2; ++p) {
            const int nbase = ((jw + p * 32) >> 5) * 16;
            const int n  = nbase + lr;
            const int np = (n & ~7) | (((n & 3) << 1) | ((n >> 2) & 1));
#pragma unroll
            for (int mt8 = 0; mt8 < 8; ++mt8)
#pragma unroll
                for (int r = 0; r < 4; ++r) {
                    const int m = m0 + wm * 128 + mt8 * 16 + quad * 4 + r;
                    float gv = acc[mt8][2 * p][r];
                    float uv = acc[mt8][2 * p + 1][r];
                    float hv = (gv / (1.0f + __expf(-gv))) * uv;
                    h[(size_t)m * NN + np] = (f16)hv;
                }
        }
    } else {
        float* __restrict__ out = (float*)Cv;
        const int cw = cbase + nb0 + wbh * 128 + wnq * 64;
#pragma unroll
        for (int nt = 0; nt < 4; ++nt)
#pragma unroll
            for (int mt8 = 0; mt8 < 8; ++mt8)
#pragma unroll
                for (int r = 0; r < 4; ++r) {
                    const int m = m0 + wm * 128 + mt8 * 16 + quad * 4 + r;
                    out[(size_t)m * K + cw + nt * 16 + lr] = acc[mt8][nt][r];
                }
    }

#undef STAGE_A
#undef STAGE_B
#undef LOAD_A
#undef LOAD_B
#undef QMFMA
#undef BAR
#undef WAITV6
#undef WAITV0
}

extern "C" void kernel_launch(void* const* d_in, const int* in_sizes, int n_in,
                              void* d_out, int out_size, void* d_ws, size_t ws_size,
                              hipStream_t stream) {
    const float* x   = (const float*)d_in[0];
    const int*   gqw = (const int*)d_in[1];
    const float* gsc = (const float*)d_in[2];
    const int*   gqz = (const int*)d_in[3];
    const int*   uqw = (const int*)d_in[4];
    const float* usc = (const float*)d_in[5];
    const int*   uqz = (const int*)d_in[6];
    const int*   dqw = (const int*)d_in[7];
    const float* dsc = (const float*)d_in[8];
    const int*   dqz = (const int*)d_in[9];
    float* out = (float*)d_out;

    const size_t HB = (size_t)M * NN * 2;   // h: 90,177,536 B
    char* ws = (char*)d_ws;
    f16* h  = (f16*)ws;
    f16* xp = (f16*)(ws + HB);              // +33.5 MB (fits, verified prev)

    convert_x_kernel<<<(M * K / 8) / 256, 256, 0, stream>>>(x, xp);

    // ---- gate/up: combined interleaved weight strips live in d_out
    // (free until the down pass). d_out = 67,108,864 B = 8192 combined
    // cols x K x 2B exactly.
    const int JC = 8192;                    // combined-col strip (2 cols/n)
    for (int j0 = 0; j0 < 2 * NN; j0 += JC) {
        int jc  = 2 * NN - j0 < JC ? 2 * NN - j0 : JC;   // 8192, 8192, 5632
        int n0  = j0 >> 1;
        int ncn = jc >> 1;                                // 4096, 4096, 2816
        f16* wc = (f16*)d_out;
        dequant_gu_strip<<<dim3(ncn / 256, K / 32), 256, 0, stream>>>(
            gqw, gsc, gqz, uqw, usc, uqz, wc, n0);
        gemm8p<0><<<dim3(M / 256, jc / 256), 512, 0, stream>>>(
            xp, wc, (void*)h, K, K / 64, j0);
    }

    // ---- down: weight strips reuse xp region (dead) + spare ws tail.
    size_t availD = ws_size - HB;                   // >= 90 MB observed
    int KC = (int)(availD / ((size_t)NN * 2));
    KC &= ~255;                                     // multiple of 256
    if (KC > K) KC = K;
    if (KC < 256) KC = 256;                         // unreachable guard
    f16* wd = (f16*)(ws + HB);
    for (int c0 = 0; c0 < K; c0 += KC) {
        int kc = K - c0 < KC ? K - c0 : KC;
        dequant_d_strip<<<dim3(kc / 256, NN / 32), 256, 0, stream>>>(
            dqw, dsc, dqz, wd, c0);
        gemm8p<1><<<dim3(M / 256, kc / 256), 512, 0, stream>>>(
            h, wd, (void*)out, NN, NN / 64, c0);
    }
}

// Round 2
// 1329.463 us; speedup vs baseline: 1.0094x; 1.0094x over previous
//
#include <hip/hip_runtime.h>
#include <hip/hip_bf16.h>

// B=2, S=2048 -> M=4096 tokens, K=4096, NN=11008, groupsize=128.
static constexpr int M  = 4096;
static constexpr int K  = 4096;
static constexpr int NN = 11008;

typedef _Float16 f16;
typedef _Float16 f16x2 __attribute__((ext_vector_type(2)));
typedef _Float16 f16x8 __attribute__((ext_vector_type(8)));
typedef float    f32x4 __attribute__((ext_vector_type(4)));

// ---------------------------------------------------------------------------
// GPTQ nibble j of an int32 covers k = 8r+j. The magic unpack emits the
// interleaved within-8 order [0,4,1,5,2,6,3,7]; all fp16 tensors (xp, Wc,
// Wd', h) use this same permutation along their reduction dim.
// Numerics: (1024+w) and (1025+z) are exact fp16 integers; their difference
// is exact; single rounding at the final mul by s.
// ---------------------------------------------------------------------------
union dq_u { f16x2 h[4]; f16x8 v; };

__device__ __forceinline__ f16x8 dq8(unsigned q, f16x2 s2, f16x2 zc2) {
    dq_u u;
    unsigned t0 = ( q         & 0x000F000Fu) | 0x64006400u;
    unsigned t1 = ((q >> 4)   & 0x000F000Fu) | 0x64006400u;
    unsigned t2 = ((q >> 8)   & 0x000F000Fu) | 0x64006400u;
    unsigned t3 = ((q >> 12)  & 0x000F000Fu) | 0x64006400u;
    u.h[0] = (__builtin_bit_cast(f16x2, t0) - zc2) * s2;
    u.h[1] = (__builtin_bit_cast(f16x2, t1) - zc2) * s2;
    u.h[2] = (__builtin_bit_cast(f16x2, t2) - zc2) * s2;
    u.h[3] = (__builtin_bit_cast(f16x2, t3) - zc2) * s2;
    return u.v;
}

// async global -> LDS, 16 B/lane; LDS dest = wave-uniform base + lane*16.
__device__ __forceinline__ void gll16(const f16* g, f16* l) {
    __builtin_amdgcn_global_load_lds(
        (const __attribute__((address_space(1))) unsigned int*)g,
        (__attribute__((address_space(3))) unsigned int*)l,
        16, 0, 0);
}

// ---------------------------------------------------------------------------
// Pre-pass: x fp32 -> fp16, permuted within each 8 along K.
// ---------------------------------------------------------------------------
__global__ __launch_bounds__(256) void convert_x_kernel(
    const float* __restrict__ x, f16* __restrict__ xp)
{
    size_t i = ((size_t)blockIdx.x * 256 + threadIdx.x) * 8;
    float4 f0 = *(const float4*)(x + i);
    float4 f1 = *(const float4*)(x + i + 4);
    f16x8 v;
    v[0] = (f16)f0.x; v[1] = (f16)f1.x;
    v[2] = (f16)f0.y; v[3] = (f16)f1.y;
    v[4] = (f16)f0.z; v[5] = (f16)f1.z;
    v[6] = (f16)f0.w; v[7] = (f16)f1.w;
    *(f16x8*)(xp + i) = v;
}

// ---------------------------------------------------------------------------
// Dequant strip: gate+up columns [n0, n0+NC) -> ONE interleaved matrix Wc:
// combined row j = (nl>>4)*32 + gu*16 + (nl&15), shape (2*NC, K) fp16.
// Even 16-blocks = gate, odd 16-blocks = up of the same 16 n's -> in the
// GEMM a wave's nt pairs (0,1),(2,3) hold (g,u) of the SAME column in the
// SAME lane. grid (NC/256, K/32).
// ---------------------------------------------------------------------------
__global__ __launch_bounds__(256) void dequant_gu_strip(
    const int* __restrict__ gqw, const float* __restrict__ gsc, const int* __restrict__ gqz,
    const int* __restrict__ uqw, const float* __restrict__ usc, const int* __restrict__ uqz,
    f16* __restrict__ wc, int n0)
{
    int nl = blockIdx.x * 256 + threadIdx.x;   // strip-local column
    int n  = n0 + nl;                          // global column
    int k0 = blockIdx.y * 32;
    int g  = k0 >> 7;
    int sh = (n & 7) * 4;

    float sgf = gsc[(size_t)g * NN + n];
    float suf = usc[(size_t)g * NN + n];
    int zg = (gqz[(size_t)g * (NN / 8) + (n >> 3)] >> sh) & 15;
    int zu = (uqz[(size_t)g * (NN / 8) + (n >> 3)] >> sh) & 15;
    f16 sgh = (f16)sgf, suh = (f16)suf;
    f16 zcg = (f16)(float)(1025 + zg);
    f16 zcu = (f16)(float)(1025 + zu);
    f16x2 s2g = {sgh, sgh}, zc2g = {zcg, zcg};
    f16x2 s2u = {suh, suh}, zc2u = {zcu, zcu};

    size_t jg = (size_t)((nl >> 4) * 32 + (nl & 15));
    size_t ju = jg + 16;

#pragma unroll
    for (int i = 0; i < 4; ++i) {
        unsigned qg = (unsigned)gqw[(size_t)(k0 / 8 + i) * NN + n];
        unsigned qu = (unsigned)uqw[(size_t)(k0 / 8 + i) * NN + n];
        *(f16x8*)&wc[jg * K + k0 + i * 8] = dq8(qg, s2g, zc2g);
        *(f16x8*)&wc[ju * K + k0 + i * 8] = dq8(qu, s2u, zc2u);
    }
}

// ---------------------------------------------------------------------------
// Dequant strip: down output columns [c0, c0+KC) -> wd as (KC, NN) fp16.
// grid (KC/256, NN/32).
// ---------------------------------------------------------------------------
__global__ __launch_bounds__(256) void dequant_d_strip(
    const int* __restrict__ dqw, const float* __restrict__ dsc, const int* __restrict__ dqz,
    f16* __restrict__ wd, int c0)
{
    int cl = blockIdx.x * 256 + threadIdx.x;
    int c  = c0 + cl;
    int n0 = blockIdx.y * 32;
    int g  = n0 >> 7;
    int sh = (c & 7) * 4;

    float sf = dsc[(size_t)g * K + c];
    int   z  = (dqz[(size_t)g * (K / 8) + (c >> 3)] >> sh) & 15;
    f16 shh = (f16)sf;
    f16 zch = (f16)(float)(1025 + z);
    f16x2 s2 = {shh, shh}, zc2 = {zch, zch};

#pragma unroll
    for (int i = 0; i < 4; ++i) {
        unsigned q = (unsigned)dqw[(size_t)(n0 / 8 + i) * K + c];
        *(f16x8*)&wd[(size_t)cl * NN + n0 + i * 8] = dq8(q, s2, zc2);
    }
}

// ---------------------------------------------------------------------------
// 256x256 8-phase GEMM (plain-HIP port of the verified m201 template).
// BK=64, 8 waves (2M x 4N), 512 threads, 128 KiB LDS (2 dbuf x 2 halves x
// 128x64 f16 for each of A,B). Per K-tile t (buffer d=t&1), 4 phases:
//   P0: ds_read A-mh0(8)+B-nh0(4); stage B1(t+1)->d^1; MFMA q(0,0); bar
//   P1: ds_read B-nh1(4);                              MFMA q(0,1); bar
//   P2: ds_read A-mh1(8); stage B0(t+2)->d;            MFMA q(1,0); bar
//   P3: stage A0,A1(t+2)->d;                           MFMA q(1,1);
//       s_waitcnt vmcnt(6); bar           // counted: 3 half-tiles in flight
// Safety invariants unchanged from R1 (verified: passed, conflicts=0).
//
// NEW (T1): XCD-aware block swizzle. HW round-robins linear block id over
// the 8 XCDs; remap so each XCD owns a CONTIGUOUS id range (m204 bijective
// formula), then decode ids through a 4-wide M supertile so each XCD's 32
// co-resident blocks (down: grid 16x16) form a 4x8 panel slab:
// per-K-tile shared line set ~384 KB << 4 MB L2 -> co-resident blocks
// L2-dedup each other's stage reads. All grids here have nwg%8==0, GX=16.
// ---------------------------------------------------------------------------
template<int EPI>
__global__ __launch_bounds__(512) void gemm8p(
    const f16* __restrict__ Ag,   // (M, SK)
    const f16* __restrict__ Bg,   // (ncols_strip, SK) strip-local
    void*      __restrict__ Cv,
    const int SK, const int NT, const int cbase)
{
    __shared__ __align__(16) f16 LA[2][2][128 * 64];  // [dbuf][m-half] 64 KB
    __shared__ __align__(16) f16 LB[2][2][128 * 64];  // [dbuf][n-half] 64 KB

    const int tid  = threadIdx.x;
    const int lane = tid & 63;
    const int wave = tid >> 6;
    const int wm   = wave >> 2;          // A (M) half owned by this wave
    const int wbh  = (wave >> 1) & 1;    // B (N) half
    const int wnq  = wave & 1;           // 64-col quarter within B half
    const int quad = lane >> 4;
    const int lr   = lane & 15;

    // ---- XCD swizzle: bijective gather + 4-wide M-supertile decode ----
    const int GX  = gridDim.x, GY = gridDim.y;
    const int nwg = GX * GY;
    const int lin = blockIdx.y * GX + blockIdx.x;      // HW dispatch order
    const int q8  = nwg >> 3, r8 = nwg & 7;
    const int xcd = lin & 7, ldx = lin >> 3;
    const int s   = (xcd < r8 ? xcd * (q8 + 1)
                              : r8 * (q8 + 1) + (xcd - r8) * q8) + ldx;
    const int span = 4 * GY;                           // GX==16, 16%4==0
    const int mb   = (s / span) * 4 + (s & 3);
    const int cb   = (s % span) >> 2;

    const int m0  = mb * 256;
    const int nb0 = cb * 256;    // strip-local col base

    // staging constants: thread covers phys bytes (r*512+tid)*16 of a
    // half-tile; prow=(r*512+tid)>>3, pchunk=tid&7; source chunk is
    // inverse-swizzled so that swizzled ds_reads see logical data.
    const int trow = tid >> 3;                    // 0..63 (r adds 64)
    const int tch  = (tid & 7) ^ (trow & 7);      // (prow&7)==(trow&7) for both r
    const size_t arow = (size_t)(m0  + trow) * SK + (size_t)tch * 8;
    const size_t brow = (size_t)(nb0 + trow) * SK + (size_t)tch * 8;
    const int lstg = wave * 512;                  // + r*4096 elems

    // frag-read chunk offsets (elems), swizzle applied: chunk ^ (row&7)
    const int c0e = ((quad) ^ (lr & 7)) * 8;
    const int c1e = ((4 + quad) ^ (lr & 7)) * 8;

    f32x4 acc[8][4];
#pragma unroll
    for (int i = 0; i < 8; ++i)
#pragma unroll
        for (int j = 0; j < 4; ++j) acc[i][j] = (f32x4){0.f, 0.f, 0.f, 0.f};

    f16x8 a_[2][4];        // [kk][mt]  current quadrant-row of A
    f16x8 b_[2][2][2];     // [nh][kk][n2]

#define STAGE_A(D_, H_, T_) do {                                              \
    const f16* s_ = Ag + arow + (size_t)(H_) * 128 * SK + (size_t)(T_) * 64;  \
    gll16(s_, &LA[D_][H_][lstg]);                                             \
    gll16(s_ + (size_t)64 * SK, &LA[D_][H_][4096 + lstg]); } while (0)

#define STAGE_B(D_, H_, T_) do {                                              \
    const f16* s_ = Bg + brow + (size_t)(H_) * 128 * SK + (size_t)(T_) * 64;  \
    gll16(s_, &LB[D_][H_][lstg]);                                             \
    gll16(s_ + (size_t)64 * SK, &LB[D_][H_][4096 + lstg]); } while (0)

#define LOAD_A(D_, MH_) do {                                                  \
    _Pragma("unroll")                                                         \
    for (int mt = 0; mt < 4; ++mt) {                                          \
        a_[0][mt] = *(const f16x8*)&LA[D_][wm][((MH_) * 64 + mt * 16 + lr) * 64 + c0e]; \
        a_[1][mt] = *(const f16x8*)&LA[D_][wm][((MH_) * 64 + mt * 16 + lr) * 64 + c1e]; \
    } } while (0)

#define LOAD_B(D_, NH_) do {                                                  \
    _Pragma("unroll")                                                         \
    for (int n2 = 0; n2 < 2; ++n2) {                                          \
        b_[NH_][0][n2] = *(const f16x8*)&LB[D_][wbh][(wnq * 64 + (NH_) * 32 + n2 * 16 + lr) * 64 + c0e]; \
        b_[NH_][1][n2] = *(const f16x8*)&LB[D_][wbh][(wnq * 64 + (NH_) * 32 + n2 * 16 + lr) * 64 + c1e]; \
    } } while (0)

#define QMFMA(MH_, NH_) do {                                                  \
    __builtin_amdgcn_s_setprio(1);                                            \
    _Pragma("unroll")                                                         \
    for (int kk = 0; kk < 2; ++kk)                                            \
    _Pragma("unroll")                                                         \
    for (int n2 = 0; n2 < 2; ++n2)                                            \
    _Pragma("unroll")                                                         \
    for (int mt = 0; mt < 4; ++mt)                                            \
        acc[(MH_) * 4 + mt][(NH_) * 2 + n2] =                                 \
            __builtin_amdgcn_mfma_f32_16x16x32_f16(                           \
                a_[kk][mt], b_[NH_][kk][n2],                                  \
                acc[(MH_) * 4 + mt][(NH_) * 2 + n2], 0, 0, 0);                \
    __builtin_amdgcn_s_setprio(0); } while (0)

#define BAR() do { __builtin_amdgcn_s_barrier();                              \
                   __builtin_amdgcn_sched_barrier(0); } while (0)
#define WAITV6() do { asm volatile("s_waitcnt vmcnt(6)" ::: "memory");        \
                      __builtin_amdgcn_sched_barrier(0); } while (0)
#define WAITV0() do { asm volatile("s_waitcnt vmcnt(0)" ::: "memory");        \
                      __builtin_amdgcn_sched_barrier(0); } while (0)

    // prologue: tile0 fully, then B0/A0/A1 of tile1 (steady in-flight set)
    STAGE_A(0, 0, 0); STAGE_A(0, 1, 0); STAGE_B(0, 0, 0); STAGE_B(0, 1, 0);
    if (NT > 1) { STAGE_B(1, 0, 1); STAGE_A(1, 0, 1); STAGE_A(1, 1, 1); }
    if (NT > 1) { WAITV6(); } else { WAITV0(); }
    BAR();

#pragma unroll 2
    for (int t = 0; t < NT; ++t) {
        const int d  = t & 1;
        const int dn = d ^ 1;
        const bool s1 = (t + 1 < NT);
        const bool s2 = (t + 2 < NT);

        // P0
        LOAD_A(d, 0);
        LOAD_B(d, 0);
        if (s1) STAGE_B(dn, 1, t + 1);
        QMFMA(0, 0);
        BAR();
        // P1
        LOAD_B(d, 1);
        QMFMA(0, 1);
        BAR();
        // P2
        LOAD_A(d, 1);
        if (s2) STAGE_B(d, 0, t + 2);
        QMFMA(1, 0);
        BAR();
        // P3
        if (s2) { STAGE_A(d, 0, t + 2); STAGE_A(d, 1, t + 2); }
        QMFMA(1, 1);
        if (s2) { WAITV6(); } else { WAITV0(); }
        BAR();
    }

    if constexpr (EPI == 0) {
        // silu(g)*u -> h fp16; nt pairs (2p, 2p+1) = (gate, up) of same n.
        f16* __restrict__ h = (f16*)Cv;
        const int jw = cbase + nb0 + wbh * 128 + wnq * 64;   // global combined col
#pragma unroll
        for (int p = 0; p < 2; ++p) {
            const int nbase = ((jw + p * 32) >> 5) * 16;
            const int n  = nbase + lr;
            const int np = (n & ~7) | (((n & 3) << 1) | ((n >> 2) & 1));
#pragma unroll
            for (int mt8 = 0; mt8 < 8; ++mt8)
#pragma unroll
                for (int r = 0; r < 4; ++r) {
                    const int m = m0 + wm * 128 + mt8 * 16 + quad * 4 + r;
                    float gv = acc[mt8][2 * p][r];
                    float uv = acc[mt8][2 * p + 1][r];
                    float hv = (gv / (1.0f + __expf(-gv))) * uv;
                    h[(size_t)m * NN + np] = (f16)hv;
                }
        }
    } else {
        float* __restrict__ out = (float*)Cv;
        const int cw = cbase + nb0 + wbh * 128 + wnq * 64;
#pragma unroll
        for (int nt = 0; nt < 4; ++nt)
#pragma unroll
            for (int mt8 = 0; mt8 < 8; ++mt8)
#pragma unroll
                for (int r = 0; r < 4; ++r) {
                    const int m = m0 + wm * 128 + mt8 * 16 + quad * 4 + r;
                    out[(size_t)m * K + cw + nt * 16 + lr] = acc[mt8][nt][r];
                }
    }

#undef STAGE_A
#undef STAGE_B
#undef LOAD_A
#undef LOAD_B
#undef QMFMA
#undef BAR
#undef WAITV6
#undef WAITV0
}

extern "C" void kernel_launch(void* const* d_in, const int* in_sizes, int n_in,
                              void* d_out, int out_size, void* d_ws, size_t ws_size,
                              hipStream_t stream) {
    const float* x   = (const float*)d_in[0];
    const int*   gqw = (const int*)d_in[1];
    const float* gsc = (const float*)d_in[2];
    const int*   gqz = (const int*)d_in[3];
    const int*   uqw = (const int*)d_in[4];
    const float* usc = (const float*)d_in[5];
    const int*   uqz = (const int*)d_in[6];
    const int*   dqw = (const int*)d_in[7];
    const float* dsc = (const float*)d_in[8];
    const int*   dqz = (const int*)d_in[9];
    float* out = (float*)d_out;

    const size_t HB = (size_t)M * NN * 2;   // h: 90,177,536 B
    char* ws = (char*)d_ws;
    f16* h  = (f16*)ws;
    f16* xp = (f16*)(ws + HB);              // +33.5 MB (fits, verified prev)

    convert_x_kernel<<<(M * K / 8) / 256, 256, 0, stream>>>(x, xp);

    // ---- gate/up: combined interleaved weight strips live in d_out
    // (free until the down pass). d_out = 67,108,864 B = 8192 combined
    // cols x K x 2B exactly.
    const int JC = 8192;                    // combined-col strip (2 cols/n)
    for (int j0 = 0; j0 < 2 * NN; j0 += JC) {
        int jc  = 2 * NN - j0 < JC ? 2 * NN - j0 : JC;   // 8192, 8192, 5632
        int n0  = j0 >> 1;
        int ncn = jc >> 1;                                // 4096, 4096, 2816
        f16* wc = (f16*)d_out;
        dequant_gu_strip<<<dim3(ncn / 256, K / 32), 256, 0, stream>>>(
            gqw, gsc, gqz, uqw, usc, uqz, wc, n0);
        gemm8p<0><<<dim3(M / 256, jc / 256), 512, 0, stream>>>(
            xp, wc, (void*)h, K, K / 64, j0);
    }

    // ---- down: weight strips reuse xp region (dead) + spare ws tail.
    size_t availD = ws_size - HB;                   // >= 90 MB observed
    int KC = (int)(availD / ((size_t)NN * 2));
    KC &= ~255;                                     // multiple of 256
    if (KC > K) KC = K;
    if (KC < 256) KC = 256;                         // unreachable guard
    f16* wd = (f16*)(ws + HB);
    for (int c0 = 0; c0 < K; c0 += KC) {
        int kc = K - c0 < KC ? K - c0 : KC;
        dequant_d_strip<<<dim3(kc / 256, NN / 32), 256, 0, stream>>>(
            dqw, dsc, dqz, wd, c0);
        gemm8p<1><<<dim3(M / 256, kc / 256), 512, 0, stream>>>(
            h, wd, out, NN, NN / 64, c0);
    }
}